// Round 8
// baseline (704.947 us; speedup 1.0000x reference)
//
#include <hip/hip_runtime.h>
#include <math.h>

#define B_ 32
#define HW_ 4096
#define N_ 16
#define C_ 128
#define F_ 512
#define ITERS_ 3
#define EPS_LN 1e-5f
#define EPS_ATTN 1e-5f

typedef __attribute__((ext_vector_type(8))) short short8;
typedef __attribute__((ext_vector_type(4))) float f32x4;

static __device__ __forceinline__ unsigned short f2b(float f) {
    union { float f; unsigned u; } v; v.f = f;
    unsigned r = v.u + 0x7fffu + ((v.u >> 16) & 1u);
    return (unsigned short)(r >> 16);
}
static __device__ __forceinline__ float blo(unsigned u) {
    union { unsigned u; float f; } v; v.u = u << 16; return v.f;
}
static __device__ __forceinline__ float bhi(unsigned u) {
    union { unsigned u; float f; } v; v.u = u & 0xffff0000u; return v.f;
}

// ---------------------------------------------------------------------------
// One-time prep: blocks 0..255 convert weights fp32->bf16; blocks 256..287
// qn_0 = (LN(query)*g+b) @ Wq^T * scale; block 288 zeroes iter counters.
// ---------------------------------------------------------------------------
__global__ __launch_bounds__(256) void k_prep(
    const float* __restrict__ Wk, const float* __restrict__ Wv,
    const float* __restrict__ wih, const float* __restrict__ whh,
    const float* __restrict__ w1, const float* __restrict__ w2,
    unsigned short* __restrict__ Wk_bf, unsigned short* __restrict__ Wv_bf,
    unsigned short* __restrict__ wih_bf, unsigned short* __restrict__ whh_bf,
    unsigned short* __restrict__ w1_bf, unsigned short* __restrict__ w2_bf,
    const float* __restrict__ query, const float* __restrict__ lnqg,
    const float* __restrict__ lnqb, const float* __restrict__ Wq,
    unsigned short* __restrict__ qn_g, int* __restrict__ cnt)
{
    __shared__ __align__(16) float xq[16 * 128];
    int tid = threadIdx.x;
    if (blockIdx.x == 288) {
        if (tid < 3 * B_) cnt[tid] = 0;
        return;
    }
    if (blockIdx.x < 256) {
        int t = blockIdx.x * 256 + tid;
        const float* src; unsigned short* dst; int off;
        if (t < 4096)       { src = Wk;  dst = Wk_bf;  off = t; }
        else if (t < 8192)  { src = Wv;  dst = Wv_bf;  off = t - 4096; }
        else if (t < 20480) { src = wih; dst = wih_bf; off = t - 8192; }
        else if (t < 32768) { src = whh; dst = whh_bf; off = t - 20480; }
        else if (t < 49152) { src = w1;  dst = w1_bf;  off = t - 32768; }
        else                { src = w2;  dst = w2_bf;  off = t - 49152; }
        float4 a = ((const float4*)src)[off];
        uint2 p;
        p.x = (unsigned)f2b(a.x) | ((unsigned)f2b(a.y) << 16);
        p.y = (unsigned)f2b(a.z) | ((unsigned)f2b(a.w) << 16);
        *(uint2*)(dst + off * 4) = p;
        return;
    }
    int b = blockIdx.x - 256;
    int n = tid >> 4, part = tid & 15;
    int row = b * 16 + n;
    const float4* x4 = (const float4*)(query + row * 128 + part * 8);
    float4 x0 = x4[0], x1 = x4[1];
    float s = x0.x + x0.y + x0.z + x0.w + x1.x + x1.y + x1.z + x1.w;
    float ss = x0.x * x0.x + x0.y * x0.y + x0.z * x0.z + x0.w * x0.w +
               x1.x * x1.x + x1.y * x1.y + x1.z * x1.z + x1.w * x1.w;
    s += __shfl_xor(s, 1); s += __shfl_xor(s, 2); s += __shfl_xor(s, 4); s += __shfl_xor(s, 8);
    ss += __shfl_xor(ss, 1); ss += __shfl_xor(ss, 2); ss += __shfl_xor(ss, 4); ss += __shfl_xor(ss, 8);
    float mean = s * (1.f / 128.f);
    float var = ss * (1.f / 128.f) - mean * mean;
    float rstd = rsqrtf(var + EPS_LN);
    const float4* g4 = (const float4*)(lnqg + part * 8);
    const float4* b4 = (const float4*)(lnqb + part * 8);
    float4 g0 = g4[0], g1 = g4[1], bb0 = b4[0], bb1 = b4[1];
    float4 o0, o1;
    o0.x = (x0.x - mean) * rstd * g0.x + bb0.x;
    o0.y = (x0.y - mean) * rstd * g0.y + bb0.y;
    o0.z = (x0.z - mean) * rstd * g0.z + bb0.z;
    o0.w = (x0.w - mean) * rstd * g0.w + bb0.w;
    o1.x = (x1.x - mean) * rstd * g1.x + bb1.x;
    o1.y = (x1.y - mean) * rstd * g1.y + bb1.y;
    o1.z = (x1.z - mean) * rstd * g1.z + bb1.z;
    o1.w = (x1.w - mean) * rstd * g1.w + bb1.w;
    float4* xrow = (float4*)&xq[n * 128];
    xrow[part * 2] = o0;
    xrow[part * 2 + 1] = o1;
    __syncthreads();
    float o[8] = {0.f, 0.f, 0.f, 0.f, 0.f, 0.f, 0.f, 0.f};
    const float4* xv4 = (const float4*)&xq[n * 128];
#pragma unroll 4
    for (int j = 0; j < 32; j++) {
        float4 xv = xv4[j];
#pragma unroll
        for (int i = 0; i < 8; i++) {
            float4 w = ((const float4*)(Wq + (part * 8 + i) * 128))[j];
            o[i] += w.x * xv.x + w.y * xv.y + w.z * xv.z + w.w * xv.w;
        }
    }
    const float scale = 0.08838834764831845f;
#pragma unroll
    for (int i = 0; i < 8; i++)
        qn_g[row * 128 + part * 8 + i] = f2b(o[i] * scale);
}

// ---------------------------------------------------------------------------
// Kernel 1 (R6 proven): kv = LN(inp); K -> [b][hw][c]; V -> [b][c][hw]
// ---------------------------------------------------------------------------
__global__ __launch_bounds__(256) void k_kvproj(
    const float* __restrict__ inp, const float* __restrict__ lng,
    const float* __restrict__ lnb, const unsigned short* __restrict__ Wk_bf,
    const unsigned short* __restrict__ Wv_bf, unsigned short* __restrict__ Kbf,
    unsigned short* __restrict__ Vt)
{
    __shared__ __align__(16) unsigned short W_lds[128 * 128];  // 32 KB
    __shared__ __align__(16) unsigned short T_lds[8960];       // 17.9 KB
    const int tid = threadIdx.x;
    const int wave = tid >> 6, lane = tid & 63;
    const int l15 = lane & 15, q4 = lane >> 4;
    const int kof = q4 * 8;
    const int tile0 = blockIdx.x * 64;
    const int b = tile0 >> 12;
    const int hwbase = tile0 & (HW_ - 1);

    const int srow = tid >> 1, shalf = tid & 1;
    const int sswz = srow & 7;

    float x[4][8];
    {
        const float* rowp = inp + (tile0 + (wave << 4) + l15) * C_;
        float s = 0.f, ss = 0.f;
#pragma unroll
        for (int ks = 0; ks < 4; ks++) {
#pragma unroll
            for (int h = 0; h < 2; h++) {
                float4 v = *(const float4*)(rowp + ks * 32 + kof + h * 4);
                x[ks][h * 4 + 0] = v.x; x[ks][h * 4 + 1] = v.y;
                x[ks][h * 4 + 2] = v.z; x[ks][h * 4 + 3] = v.w;
                s += v.x + v.y + v.z + v.w;
                ss += v.x * v.x + v.y * v.y + v.z * v.z + v.w * v.w;
            }
        }
        s += __shfl_xor(s, 16);  s += __shfl_xor(s, 32);
        ss += __shfl_xor(ss, 16); ss += __shfl_xor(ss, 32);
        float mean = s * (1.f / 128.f);
        float var = ss * (1.f / 128.f) - mean * mean;
        float rstd = rsqrtf(var + EPS_LN);
#pragma unroll
        for (int ks = 0; ks < 4; ks++) {
#pragma unroll
            for (int h = 0; h < 2; h++) {
                float4 g = *(const float4*)(lng + ks * 32 + kof + h * 4);
                float4 bb = *(const float4*)(lnb + ks * 32 + kof + h * 4);
                x[ks][h * 4 + 0] = (x[ks][h * 4 + 0] - mean) * rstd * g.x + bb.x;
                x[ks][h * 4 + 1] = (x[ks][h * 4 + 1] - mean) * rstd * g.y + bb.y;
                x[ks][h * 4 + 2] = (x[ks][h * 4 + 2] - mean) * rstd * g.z + bb.z;
                x[ks][h * 4 + 3] = (x[ks][h * 4 + 3] - mean) * rstd * g.w + bb.w;
            }
        }
    }
    short8 af[4];
#pragma unroll
    for (int ks = 0; ks < 4; ks++) {
        union { short8 s8; unsigned u[4]; } p;
#pragma unroll
        for (int j = 0; j < 4; j++)
            p.u[j] = (unsigned)f2b(x[ks][2 * j]) | ((unsigned)f2b(x[ks][2 * j + 1]) << 16);
        af[ks] = p.s8;
    }

    {
        const uint4* gW = (const uint4*)Wk_bf;
#pragma unroll
        for (int j = 0; j < 8; j++) {
            int c = shalf * 8 + j;
            uint4 w = gW[srow * 16 + c];
            *(uint4*)&W_lds[srow * 128 + (c ^ sswz) * 8] = w;
        }
    }
    __syncthreads();

    f32x4 acc[8];
#pragma unroll
    for (int nt = 0; nt < 8; nt++) {
        acc[nt] = (f32x4){0.f, 0.f, 0.f, 0.f};
#pragma unroll
        for (int ks = 0; ks < 4; ks++) {
            short8 bf = *(const short8*)&W_lds[(nt * 16 + l15) * 128 + ((ks * 4 + q4) ^ (l15 & 7)) * 8];
            acc[nt] = __builtin_amdgcn_mfma_f32_16x16x32_bf16(af[ks], bf, acc[nt], 0, 0, 0);
        }
    }
#pragma unroll
    for (int nt = 0; nt < 8; nt++) {
        int c = nt * 16 + l15;
#pragma unroll
        for (int i = 0; i < 4; i++)
            T_lds[((wave << 4) + (q4 << 2) + i) * 132 + c] = f2b(acc[nt][i]);
    }
    __syncthreads();
    {
        int row = tid >> 2, part = tid & 3;
        uint4* dst = (uint4*)&Kbf[(b * HW_ + hwbase + row) * C_ + part * 32];
#pragma unroll
        for (int j = 0; j < 4; j++)
            dst[j] = *(const uint4*)&T_lds[row * 132 + part * 32 + j * 8];
    }
    {
        const uint4* gW = (const uint4*)Wv_bf;
#pragma unroll
        for (int j = 0; j < 8; j++) {
            int c = shalf * 8 + j;
            uint4 w = gW[srow * 16 + c];
            *(uint4*)&W_lds[srow * 128 + (c ^ sswz) * 8] = w;
        }
    }
    __syncthreads();
#pragma unroll
    for (int nt = 0; nt < 8; nt++) {
        acc[nt] = (f32x4){0.f, 0.f, 0.f, 0.f};
#pragma unroll
        for (int ks = 0; ks < 4; ks++) {
            short8 bf = *(const short8*)&W_lds[(nt * 16 + l15) * 128 + ((ks * 4 + q4) ^ (l15 & 7)) * 8];
            acc[nt] = __builtin_amdgcn_mfma_f32_16x16x32_bf16(af[ks], bf, acc[nt], 0, 0, 0);
        }
    }
    __syncthreads();
#pragma unroll
    for (int nt = 0; nt < 8; nt++) {
        int c = nt * 16 + l15;
#pragma unroll
        for (int i = 0; i < 4; i++)
            T_lds[c * 70 + (wave << 4) + (q4 << 2) + i] = f2b(acc[nt][i]);
    }
    __syncthreads();
    {
        int c = tid >> 1, half = tid & 1;
        uint4* dst = (uint4*)&Vt[(b * C_ + c) * HW_ + hwbase + half * 32];
#pragma unroll
        for (int j = 0; j < 4; j++)
            dst[j] = *(const uint4*)&T_lds[c * 70 + half * 32 + j * 8];
    }
}

// ---------------------------------------------------------------------------
// Fused per-iter kernel, grid (40, B), 128 threads, __launch_bounds__(128,3).
// chunks 0..31: R6 attn (64 hw/wave) -> Upart/rspart export -> fence+count.
// chunks 32..39: spin on cnt[b]==32, then tail for 2 rows (GRU+LN+FFN+qn).
// Co-residency guaranteed: 1280 blocks <= 6 blocks/CU * 256 CU.
// ---------------------------------------------------------------------------
__global__ __launch_bounds__(128, 3) void k_attn_tail(
    const unsigned short* __restrict__ qn_g_ro, const unsigned short* __restrict__ Kbf,
    const unsigned short* __restrict__ Vt, float* __restrict__ Upart,
    float* __restrict__ rspart, float* __restrict__ a0_out,
    const float* __restrict__ hsrc, float* __restrict__ q_buf,
    const unsigned short* __restrict__ wih_bf, const unsigned short* __restrict__ whh_bf,
    const float* __restrict__ bih, const float* __restrict__ bhh,
    const float* __restrict__ ln2g, const float* __restrict__ ln2b,
    const unsigned short* __restrict__ w1_bf, const float* __restrict__ b1,
    const unsigned short* __restrict__ w2_bf, const float* __restrict__ b2,
    const float* __restrict__ lnqg, const float* __restrict__ lnqb,
    const float* __restrict__ Wq, unsigned short* __restrict__ qn_g_w,
    float* __restrict__ out_q, int* __restrict__ cnt, int last)
{
    __shared__ __align__(16) char smem[21760];
    const int b = blockIdx.y, chunk = blockIdx.x;
    const int tid = threadIdx.x;

    if (chunk >= 32) {
        // ================= TAIL role: rows q0, q0+1 of batch b =============
        float (*u_l)[128]  = (float (*)[128])smem;            // 1 KB
        float (*h_l)[128]  = (float (*)[128])(smem + 1024);   // 1 KB
        float (*g_l)[768]  = (float (*)[768])(smem + 2048);   // 6 KB
        float (*z_l)[128]  = (float (*)[128])(smem + 8192);   // 1 KB
        float (*y_l)[128]  = (float (*)[128])(smem + 9216);   // 1 KB
        float (*h1_l)[512] = (float (*)[512])(smem + 10240);  // 4 KB
        float* stats = (float*)(smem + 14336);                // 4 floats
        float* srs2  = (float*)(smem + 14352);                // 2 floats
        const int q0 = (chunk - 32) * 2;
        const int wv = tid >> 6, ln = tid & 63;

        if (tid == 0) {
            while (__hip_atomic_load(cnt + b, __ATOMIC_ACQUIRE, __HIP_MEMORY_SCOPE_AGENT) < 32)
                __builtin_amdgcn_s_sleep(2);
        }
        __syncthreads();
        __threadfence();

        // ---- u = (sum Upart)/(sum rspart + eps), h = hsrc ----
        float us[2];
#pragma unroll
        for (int r = 0; r < 2; r++) {
            float s = 0.f;
#pragma unroll 8
            for (int ch = 0; ch < 32; ch++)
                s += Upart[(b * 32 + ch) * 2048 + (q0 + r) * 128 + tid];
            us[r] = s;
        }
        {
            float v = (ln < 32) ? rspart[(b * 32 + ln) * 16 + q0 + wv] : 0.f;
#pragma unroll
            for (int off = 1; off < 64; off <<= 1) v += __shfl_xor(v, off);
            if (ln == 0) srs2[wv] = v;
        }
        __syncthreads();
#pragma unroll
        for (int r = 0; r < 2; r++) {
            u_l[r][tid] = us[r] / (srs2[r] + EPS_ATTN);
            h_l[r][tid] = hsrc[(b * 16 + q0 + r) * 128 + tid];
        }
        __syncthreads();
        // ---- GRU gates: 6 outputs/thread, both rows share weight row ----
#pragma unroll
        for (int oo = 0; oo < 6; oo++) {
            int o = tid + oo * 128;
            const unsigned short* wrow;
            const float* s0; const float* s1; float bias;
            if (o < 384) { wrow = wih_bf + o * 128; s0 = u_l[0]; s1 = u_l[1]; bias = bih[o]; }
            else         { wrow = whh_bf + (o - 384) * 128; s0 = h_l[0]; s1 = h_l[1]; bias = bhh[o - 384]; }
            const uint4* w4 = (const uint4*)wrow;
            const float4* a4 = (const float4*)s0;
            const float4* b4 = (const float4*)s1;
            float acc0 = 0.f, acc1 = 0.f;
#pragma unroll 8
            for (int j = 0; j < 16; j++) {
                uint4 w = w4[j];
                float w0 = blo(w.x), w1v = bhi(w.x), w2v = blo(w.y), w3 = bhi(w.y);
                float w4v = blo(w.z), w5 = bhi(w.z), w6 = blo(w.w), w7 = bhi(w.w);
                float4 aA = a4[2 * j], aB = a4[2 * j + 1];
                float4 bA = b4[2 * j], bB = b4[2 * j + 1];
                acc0 += w0 * aA.x + w1v * aA.y + w2v * aA.z + w3 * aA.w
                      + w4v * aB.x + w5 * aB.y + w6 * aB.z + w7 * aB.w;
                acc1 += w0 * bA.x + w1v * bA.y + w2v * bA.z + w3 * bA.w
                      + w4v * bB.x + w5 * bB.y + w6 * bB.z + w7 * bB.w;
            }
            g_l[0][o] = acc0 + bias;
            g_l[1][o] = acc1 + bias;
        }
        __syncthreads();
#pragma unroll
        for (int r = 0; r < 2; r++) {
            int c = tid;
            float ir = g_l[r][c], iz = g_l[r][128 + c], in_ = g_l[r][256 + c];
            float hr = g_l[r][384 + c], hz = g_l[r][512 + c], hn = g_l[r][640 + c];
            float rr = 1.f / (1.f + expf(-(ir + hr)));
            float zz = 1.f / (1.f + expf(-(iz + hz)));
            float nn = tanhf(in_ + rr * hn);
            y_l[r][c] = (1.f - zz) * nn + zz * h_l[r][c];
        }
        __syncthreads();
        {
            float v0 = y_l[wv][ln], v1 = y_l[wv][ln + 64];
            float s = v0 + v1, ss = v0 * v0 + v1 * v1;
#pragma unroll
            for (int off = 1; off < 64; off <<= 1) {
                s += __shfl_xor(s, off);
                ss += __shfl_xor(ss, off);
            }
            if (ln == 0) {
                float mean = s * (1.f / 128.f);
                float var = ss * (1.f / 128.f) - mean * mean;
                stats[wv * 2] = mean;
                stats[wv * 2 + 1] = rsqrtf(var + EPS_LN);
            }
        }
        __syncthreads();
#pragma unroll
        for (int r = 0; r < 2; r++)
            z_l[r][tid] = (y_l[r][tid] - stats[r * 2]) * stats[r * 2 + 1] * ln2g[tid] + ln2b[tid];
        __syncthreads();
        // ---- FFN1: 4 f/thread ----
#pragma unroll
        for (int ff = 0; ff < 4; ff++) {
            int f = tid + ff * 128;
            const uint4* w4 = (const uint4*)(w1_bf + f * 128);
            const float4* a4 = (const float4*)z_l[0];
            const float4* b4 = (const float4*)z_l[1];
            float acc0 = 0.f, acc1 = 0.f;
#pragma unroll 8
            for (int j = 0; j < 16; j++) {
                uint4 w = w4[j];
                float w0 = blo(w.x), w1v = bhi(w.x), w2v = blo(w.y), w3 = bhi(w.y);
                float w4v = blo(w.z), w5 = bhi(w.z), w6 = blo(w.w), w7 = bhi(w.w);
                float4 aA = a4[2 * j], aB = a4[2 * j + 1];
                float4 bA = b4[2 * j], bB = b4[2 * j + 1];
                acc0 += w0 * aA.x + w1v * aA.y + w2v * aA.z + w3 * aA.w
                      + w4v * aB.x + w5 * aB.y + w6 * aB.z + w7 * aB.w;
                acc1 += w0 * bA.x + w1v * bA.y + w2v * bA.z + w3 * bA.w
                      + w4v * bB.x + w5 * bB.y + w6 * bB.z + w7 * bB.w;
            }
            float bv = b1[f];
            h1_l[0][f] = fmaxf(acc0 + bv, 0.f);
            h1_l[1][f] = fmaxf(acc1 + bv, 0.f);
        }
        __syncthreads();
        // ---- FFN2 + residual: c = tid, full 512-dot per row ----
        float q_new[2];
        {
            const uint4* w4 = (const uint4*)(w2_bf + tid * 512);
            const float4* hA4 = (const float4*)h1_l[0];
            const float4* hB4 = (const float4*)h1_l[1];
            float acc0 = 0.f, acc1 = 0.f;
#pragma unroll 8
            for (int j = 0; j < 64; j++) {
                uint4 w = w4[j];
                float w0 = blo(w.x), w1v = bhi(w.x), w2v = blo(w.y), w3 = bhi(w.y);
                float w4v = blo(w.z), w5 = bhi(w.z), w6 = blo(w.w), w7 = bhi(w.w);
                float4 aA = hA4[2 * j], aB = hA4[2 * j + 1];
                float4 bA = hB4[2 * j], bB = hB4[2 * j + 1];
                acc0 += w0 * aA.x + w1v * aA.y + w2v * aA.z + w3 * aA.w
                      + w4v * aB.x + w5 * aB.y + w6 * aB.z + w7 * aB.w;
                acc1 += w0 * bA.x + w1v * bA.y + w2v * bA.z + w3 * bA.w
                      + w4v * bB.x + w5 * bB.y + w6 * bB.z + w7 * bB.w;
            }
            float bv = b2[tid];
            q_new[0] = y_l[0][tid] + acc0 + bv;
            q_new[1] = y_l[1][tid] + acc1 + bv;
#pragma unroll
            for (int r = 0; r < 2; r++) {
                int row = b * 16 + q0 + r;
                q_buf[row * 128 + tid] = q_new[r];
                if (last) out_q[row * 128 + tid] = q_new[r];
            }
        }
        if (!last) {
            __syncthreads();
#pragma unroll
            for (int r = 0; r < 2; r++) y_l[r][tid] = q_new[r];
            __syncthreads();
            {
                float v0 = y_l[wv][ln], v1 = y_l[wv][ln + 64];
                float s = v0 + v1, ss = v0 * v0 + v1 * v1;
#pragma unroll
                for (int off = 1; off < 64; off <<= 1) {
                    s += __shfl_xor(s, off);
                    ss += __shfl_xor(ss, off);
                }
                if (ln == 0) {
                    float mean = s * (1.f / 128.f);
                    float var = ss * (1.f / 128.f) - mean * mean;
                    stats[wv * 2] = mean;
                    stats[wv * 2 + 1] = rsqrtf(var + EPS_LN);
                }
            }
            __syncthreads();
#pragma unroll
            for (int r = 0; r < 2; r++)
                z_l[r][tid] = (q_new[r] - stats[r * 2]) * stats[r * 2 + 1] * lnqg[tid] + lnqb[tid];
            __syncthreads();
            {
                const float4* w4 = (const float4*)(Wq + tid * 128);
                const float4* zA = (const float4*)z_l[0];
                const float4* zB = (const float4*)z_l[1];
                float acc0 = 0.f, acc1 = 0.f;
#pragma unroll 8
                for (int j = 0; j < 32; j++) {
                    float4 w = w4[j], a = zA[j], bb = zB[j];
                    acc0 += w.x * a.x + w.y * a.y + w.z * a.z + w.w * a.w;
                    acc1 += w.x * bb.x + w.y * bb.y + w.z * bb.z + w.w * bb.w;
                }
#pragma unroll
                for (int r = 0; r < 2; r++)
                    qn_g_w[(b * 16 + q0 + r) * 128 + tid] =
                        f2b((r == 0 ? acc0 : acc1) * 0.08838834764831845f);
            }
        }
        return;
    }

    // ===================== ATTN role (R6 body) =============================
    float (*Ul)[16 * 132] = (float (*)[16 * 132])smem;                    // 16.9 KB
    unsigned short (*Pb)[16 * 72] = (unsigned short (*)[16 * 72])(smem + 16896); // 4.6 KB
    float (*rsw)[16] = (float (*)[16])(smem + 21504);                     // 128 B
    const int wave = tid >> 6, lane = tid & 63;
    const int l15 = lane & 15, q4 = lane >> 4;
    const int kof = q4 * 8;
    const int hwb = chunk * 128 + wave * 64;

    short8 aq[4];
#pragma unroll
    for (int ks = 0; ks < 4; ks++)
        aq[ks] = *(const short8*)&qn_g_ro[(b * 16 + l15) * 128 + ks * 32 + kof];
    short8 av[8][2];
#pragma unroll
    for (int ct = 0; ct < 8; ct++) {
#pragma unroll
        for (int k2 = 0; k2 < 2; k2++)
            av[ct][k2] = *(const short8*)&Vt[(b * C_ + ct * 16 + l15) * HW_ + hwb + k2 * 32 + kof];
    }

    unsigned short* Pw = &Pb[wave][0];
    float rs[4] = {0.f, 0.f, 0.f, 0.f};
#pragma unroll
    for (int s = 0; s < 4; s++) {
        int hwt = hwb + s * 16;
        f32x4 sa = {0.f, 0.f, 0.f, 0.f};
#pragma unroll
        for (int ks = 0; ks < 4; ks++) {
            short8 bk = *(const short8*)&Kbf[(b * HW_ + hwt + l15) * C_ + ks * 32 + kof];
            sa = __builtin_amdgcn_mfma_f32_16x16x32_bf16(aq[ks], bk, sa, 0, 0, 0);
        }
        float mx = fmaxf(fmaxf(sa[0], sa[1]), fmaxf(sa[2], sa[3]));
        mx = fmaxf(mx, __shfl_xor(mx, 16));
        mx = fmaxf(mx, __shfl_xor(mx, 32));
        float e[4]; float ssum = 0.f;
#pragma unroll
        for (int i = 0; i < 4; i++) { e[i] = __expf(sa[i] - mx); ssum += e[i]; }
        ssum += __shfl_xor(ssum, 16);
        ssum += __shfl_xor(ssum, 32);
        float inv = 1.f / ssum;
#pragma unroll
        for (int i = 0; i < 4; i++) {
            float a0v = e[i] * inv;
            rs[i] += a0v;
            if (last) a0_out[(b * 16 + q4 * 4 + i) * HW_ + hwt + l15] = a0v;
            Pw[(q4 * 4 + i) * 72 + s * 16 + l15] = f2b(a0v);
        }
    }
#pragma unroll
    for (int i = 0; i < 4; i++) {
        rs[i] += __shfl_xor(rs[i], 1);
        rs[i] += __shfl_xor(rs[i], 2);
        rs[i] += __shfl_xor(rs[i], 4);
        rs[i] += __shfl_xor(rs[i], 8);
    }
    if (l15 == 0) {
#pragma unroll
        for (int i = 0; i < 4; i++) rsw[wave][q4 * 4 + i] = rs[i];
    }
    short8 bp0 = *(const short8*)&Pw[l15 * 72 + kof];
    short8 bp1 = *(const short8*)&Pw[l15 * 72 + 32 + kof];
#pragma unroll
    for (int ct = 0; ct < 8; ct++) {
        f32x4 ua = __builtin_amdgcn_mfma_f32_16x16x32_bf16(av[ct][0], bp0, (f32x4){0.f, 0.f, 0.f, 0.f}, 0, 0, 0);
        ua = __builtin_amdgcn_mfma_f32_16x16x32_bf16(av[ct][1], bp1, ua, 0, 0, 0);
        *(f32x4*)&Ul[wave][l15 * 132 + ct * 16 + (q4 << 2)] = ua;
    }
    __syncthreads();
    {
        float* up = Upart + (b * 32 + chunk) * 2048;
#pragma unroll
        for (int k = 0; k < 16; k++) {
            int idx = tid + k * 128;          // idx = q*128 + c
            int q = idx >> 7, c = idx & 127;
            up[idx] = Ul[0][q * 132 + c] + Ul[1][q * 132 + c];
        }
        if (tid < 16)
            rspart[(b * 32 + chunk) * 16 + tid] = rsw[0][tid] + rsw[1][tid];
    }
    __threadfence();
    __syncthreads();
    if (tid == 0)
        __hip_atomic_fetch_add(cnt + b, 1, __ATOMIC_RELEASE, __HIP_MEMORY_SCOPE_AGENT);
}

// ---------------------------------------------------------------------------
extern "C" void kernel_launch(void* const* d_in, const int* in_sizes, int n_in,
                              void* d_out, int out_size, void* d_ws, size_t ws_size,
                              hipStream_t stream) {
    const float* inp     = (const float*)d_in[0];
    const float* query   = (const float*)d_in[1];
    const float* ln_kv_g = (const float*)d_in[2];
    const float* ln_kv_b = (const float*)d_in[3];
    const float* Wk      = (const float*)d_in[4];
    const float* Wv      = (const float*)d_in[5];
    const float* ln_q_g  = (const float*)d_in[6];
    const float* ln_q_b  = (const float*)d_in[7];
    const float* Wq      = (const float*)d_in[8];
    const float* gru_wih = (const float*)d_in[9];
    const float* gru_whh = (const float*)d_in[10];
    const float* gru_bih = (const float*)d_in[11];
    const float* gru_bhh = (const float*)d_in[12];
    const float* ln2_g   = (const float*)d_in[13];
    const float* ln2_b   = (const float*)d_in[14];
    const float* ffn_w1  = (const float*)d_in[15];
    const float* ffn_b1  = (const float*)d_in[16];
    const float* ffn_w2  = (const float*)d_in[17];
    const float* ffn_b2  = (const float*)d_in[18];

    char* ws = (char*)d_ws;
    unsigned short* Kbf    = (unsigned short*)ws;                  // 33554432
    unsigned short* Vt     = (unsigned short*)(ws + 33554432);     // 33554432
    float* q_buf           = (float*)(ws + 67108864);              // 262144
    float* Upart           = (float*)(ws + 67371008);              // 8388608
    float* rspart          = (float*)(ws + 75759616);              // 65536
    unsigned short* qn_g   = (unsigned short*)(ws + 75825152);     // 131072
    unsigned short* Wk_bf  = (unsigned short*)(ws + 75956224);     // 32768
    unsigned short* Wv_bf  = (unsigned short*)(ws + 75988992);     // 32768
    unsigned short* wih_bf = (unsigned short*)(ws + 76021760);     // 98304
    unsigned short* whh_bf = (unsigned short*)(ws + 76120064);     // 98304
    unsigned short* w1_bf  = (unsigned short*)(ws + 76218368);     // 131072
    unsigned short* w2_bf  = (unsigned short*)(ws + 76349440);     // 131072
    int* cnt               = (int*)(ws + 76480512);                // 384

    float* out_q  = (float*)d_out;
    float* out_a0 = out_q + B_ * N_ * C_;

    k_prep<<<dim3(289), dim3(256), 0, stream>>>(
        Wk, Wv, gru_wih, gru_whh, ffn_w1, ffn_w2,
        Wk_bf, Wv_bf, wih_bf, whh_bf, w1_bf, w2_bf,
        query, ln_q_g, ln_q_b, Wq, qn_g, cnt);
    k_kvproj<<<dim3((B_ * HW_) / 64), dim3(256), 0, stream>>>(
        inp, ln_kv_g, ln_kv_b, Wk_bf, Wv_bf, Kbf, Vt);

    for (int it = 0; it < ITERS_; it++) {
        int last = (it == ITERS_ - 1) ? 1 : 0;
        const float* hsrc = (it == 0) ? query : q_buf;
        k_attn_tail<<<dim3(40, B_), dim3(128), 0, stream>>>(
            qn_g, Kbf, Vt, Upart, rspart, out_a0,
            hsrc, q_buf, wih_bf, whh_bf, gru_bih, gru_bhh,
            ln2_g, ln2_b, w1_bf, ffn_b1, w2_bf, ffn_b2,
            ln_q_g, ln_q_b, Wq, qn_g, out_q, cnt + it * B_, last);
    }
}